// Round 1
// baseline (1173.473 us; speedup 1.0000x reference)
//
#include <hip/hip_runtime.h>
#include <stdint.h>

typedef __attribute__((ext_vector_type(8))) short s8v;
typedef __attribute__((ext_vector_type(4))) float f4v;

// ---- problem geometry ----
// x:(512,260) conv1-> h:(512,64,130) conv2-> z_e:(512,128,65)=z:(512,8320)
// codebook:(8192,8320); scores s_j = ||c_j||^2 - 2 z.c_j ; argmin
// outputs: emb[1], x_hat[512*260], mt[512*16], adv[512*16], perp[1]
#define OUT_XHAT 1
#define OUT_MT   133121
#define OUT_ADV  141313
#define OUT_PERP 149505

// ---- workspace layout (float offsets) ----
#define WS_COUNTS   0            // 8192
#define WS_EMB      8192         // 1
#define WS_A1       8256         // 131072 (zeroed region ends 139328)
#define WS_ZERO_N   139328
#define WS_H        139328       // 4,259,840 (h, later reused as hd)
#define WS_ZE       4399168      // 4,259,840
#define WS_SC0      8659008      // 4,194,304
#define WS_SC1      12853312     // 4,194,304
#define WS_ZQ       8659008      // alias over SC0/SC1 (scores dead by then)
#define WS_W2T      17047616     // 32768
#define WS_WE       17080384     // 16384
#define WS_WO       17096768     // 16384
#define WS_W2TA     17113152     // 32768
#define WS_ROWL1    17145920     // 512
#define WS_IDX      17146432     // 512 ints
#define WS_ZBF      17146944     // 8,519,680 shorts (bf16 z)

__device__ __forceinline__ short f2bf(float f) {
  uint32_t u = __float_as_uint(f);
  u = (u + 0x7FFFu + ((u >> 16) & 1u)) >> 16;  // RNE truncate to bf16
  return (short)u;
}

// ---------------- init / weight prep ----------------
__global__ void k_init(float* w) {
  int id = blockIdx.x * 256 + threadIdx.x;
  if (id < WS_ZERO_N) w[id] = 0.f;
}

__global__ void k_prep(const float* __restrict__ c2w, const float* __restrict__ d1w,
                       const float* __restrict__ aw2, float* __restrict__ w2t,
                       float* __restrict__ We, float* __restrict__ Wo,
                       float* __restrict__ w2ta) {
  int id = blockIdx.x * 256 + threadIdx.x;
  if (id < 32768) {
    int c = id & 127, ik = id >> 7;
    int i = ik >> 2, k = ik & 3;
    w2t[id] = c2w[(c * 64 + i) * 4 + k];     // w2t[(i*4+k)*128+c]
    int n = id & 127, kk = id >> 7;
    w2ta[id] = aw2[n * 256 + kk];            // w2ta[k*128+n]
  }
  if (id < 16384) {
    int o = id & 63, is = id >> 6;
    int i = is >> 1, s = is & 1;
    We[id] = d1w[(i * 64 + o) * 4 + (3 - 2 * s)];
    Wo[id] = d1w[(i * 64 + o) * 4 + (2 - 2 * s)];
  }
}

// ---------------- conv1 ----------------
__global__ void k_conv1(const float* __restrict__ x, const float* __restrict__ w,
                        const float* __restrict__ bias, float* __restrict__ h) {
  int id = blockIdx.x * 256 + threadIdx.x;
  if (id >= 512 * 64 * 130) return;
  int t = id % 130, bc = id / 130;
  int c = bc & 63, b = bc >> 6;
  const float* xb = x + b * 260;
  float acc = bias[c];
  int p0 = 2 * t - 1;
#pragma unroll
  for (int k = 0; k < 4; ++k) {
    int p = p0 + k;
    float xv = (p >= 0 && p < 260) ? xb[p] : 0.f;
    acc = fmaf(xv, w[c * 4 + k], acc);
  }
  h[id] = fmaxf(acc, 0.f);
}

// ---------------- generic gather-GEMM (conv2 / deconv1 even / odd) --------
// out[(b, n, t)] = act(bias[n] + sum_j gather(src)[(b,t)][j] * wt[j][n])
// gather: c=j>>kdiv_shift, kk=j&mask, p=(t<<tmul_shift)+toff+kk, zero OOB.
template <int N>
__global__ __launch_bounds__(256) void k_gemm_gather(
    const float* __restrict__ src, int Cin, int Tsrc, int kdiv_shift,
    int tmul_shift, int toff, const float* __restrict__ wt,
    const float* __restrict__ bias, float* __restrict__ out, int out_cstride,
    int out_tmul, int out_toff, int do_relu) {
  const int NPT = N / 16;
  __shared__ float At[32 * 64];
  __shared__ float Bt[32 * N];
  int tid = threadIdx.x;
  int row0 = blockIdx.x * 64;
  int tm = (tid & 15) * 4;
  int tn = (tid >> 4) * NPT;
  int sr = tid & 63;
  int sj0 = (tid >> 6) * 8;
  int rowm = row0 + sr;
  int gb = rowm / 65;
  int gt = rowm - gb * 65;
  const float* sbase = src + (size_t)gb * Cin * Tsrc;
  int tpos = (gt << tmul_shift) + toff;
  int kmask = (1 << kdiv_shift) - 1;
  int bkr = tid >> 3;
  int bnc = (tid & 7) * (N / 8);

  float acc[4][NPT];
#pragma unroll
  for (int i = 0; i < 4; ++i)
#pragma unroll
    for (int j = 0; j < NPT; ++j) acc[i][j] = 0.f;

  for (int k0 = 0; k0 < 256; k0 += 32) {
    float av[8];
#pragma unroll
    for (int u = 0; u < 8; ++u) {
      int jj = k0 + sj0 + u;
      int cc = jj >> kdiv_shift;
      int kk = jj & kmask;
      int p = tpos + kk;
      av[u] = (p >= 0 && p < Tsrc) ? sbase[cc * Tsrc + p] : 0.f;
    }
    float bvv[N / 8];
#pragma unroll
    for (int u = 0; u < N / 8; ++u) bvv[u] = wt[(k0 + bkr) * N + bnc + u];
    __syncthreads();
#pragma unroll
    for (int u = 0; u < 8; ++u) At[(sj0 + u) * 64 + sr] = av[u];
#pragma unroll
    for (int u = 0; u < N / 8; ++u) Bt[bkr * N + bnc + u] = bvv[u];
    __syncthreads();
#pragma unroll
    for (int kk = 0; kk < 32; ++kk) {
      float a0 = At[kk * 64 + tm + 0];
      float a1 = At[kk * 64 + tm + 1];
      float a2 = At[kk * 64 + tm + 2];
      float a3 = At[kk * 64 + tm + 3];
#pragma unroll
      for (int j = 0; j < NPT; ++j) {
        float bv = Bt[kk * N + tn + j];
        acc[0][j] = fmaf(a0, bv, acc[0][j]);
        acc[1][j] = fmaf(a1, bv, acc[1][j]);
        acc[2][j] = fmaf(a2, bv, acc[2][j]);
        acc[3][j] = fmaf(a3, bv, acc[3][j]);
      }
    }
  }
#pragma unroll
  for (int i = 0; i < 4; ++i) {
    int rr = row0 + tm + i;
    int b = rr / 65, t = rr - b * 65;
#pragma unroll
    for (int j = 0; j < NPT; ++j) {
      int n = tn + j;
      float v = acc[i][j] + bias[n];
      if (do_relu) v = fmaxf(v, 0.f);
      out[(size_t)b * N * out_cstride + (size_t)n * out_cstride +
          t * out_tmul + out_toff] = v;
    }
  }
}

// ---------------- pack z to bf16 + row L1 norms ----------------
__global__ void k_pack(const float* __restrict__ z_e, short* __restrict__ zb,
                       float* __restrict__ rowl1) {
  __shared__ float red[256];
  int b = blockIdx.x, tid = threadIdx.x;
  const float* zr = z_e + (size_t)b * 8320;
  short* zo = zb + (size_t)b * 8320;
  float l1 = 0.f;
  for (int k = tid; k < 8320; k += 256) {
    float f = zr[k];
    zo[k] = f2bf(f);
    l1 += fabsf(f);
  }
  red[tid] = l1;
  __syncthreads();
  for (int st = 128; st > 0; st >>= 1) {
    if (tid < st) red[tid] += red[tid + st];
    __syncthreads();
  }
  if (tid == 0) rowl1[b] = red[0];
}

// ---------------- scores GEMM: bf16 MFMA, M_tile=256 N_tile=64 Ksplit=2 ----
// sc[m][n] += -2 * (z.c partial) + (||c||^2 partial)
__global__ __launch_bounds__(256) void k_scores(const float* __restrict__ cb,
                                                const short* __restrict__ zb,
                                                float* __restrict__ sc0,
                                                float* __restrict__ sc1) {
  __shared__ short As[4 * 256 * 8];  // [kc][m][8]
  __shared__ short Bs[4 * 64 * 8];   // [kc][n][8]
  __shared__ float cnp[256];
  __shared__ float cnl[64];
  int bid = blockIdx.x;
  int kh = bid & 1, mt = (bid >> 1) & 1, nt = bid >> 2;
  int tid = threadIdx.x;
  int wave = tid >> 6, lane = tid & 63;
  int q = lane >> 4, r16 = lane & 15;
  int n0 = nt * 64, m0 = mt * 256, kb = kh * 4160;

  const short* zrow = zb + (size_t)(m0 + tid) * 8320 + kb;
  const float* crow = cb + (size_t)(n0 + lane) * 8320 + kb + wave * 8;

  f4v acc[4][4];
#pragma unroll
  for (int i = 0; i < 4; ++i)
#pragma unroll
    for (int j = 0; j < 4; ++j)
#pragma unroll
      for (int r = 0; r < 4; ++r) acc[i][j][r] = 0.f;
  float cna = 0.f;

  for (int ks = 0; ks < 130; ++ks) {
    const short* zp = zrow + ks * 32;
    int4 za0 = *(const int4*)(zp);
    int4 za1 = *(const int4*)(zp + 8);
    int4 za2 = *(const int4*)(zp + 16);
    int4 za3 = *(const int4*)(zp + 24);
    const float* cp = crow + ks * 32;
    float4 cf0 = *(const float4*)(cp);
    float4 cf1 = *(const float4*)(cp + 4);
    __syncthreads();
    *(int4*)&As[(0 * 256 + tid) * 8] = za0;
    *(int4*)&As[(1 * 256 + tid) * 8] = za1;
    *(int4*)&As[(2 * 256 + tid) * 8] = za2;
    *(int4*)&As[(3 * 256 + tid) * 8] = za3;
    union { short s[8]; int4 v; } u;
    u.s[0] = f2bf(cf0.x); u.s[1] = f2bf(cf0.y);
    u.s[2] = f2bf(cf0.z); u.s[3] = f2bf(cf0.w);
    u.s[4] = f2bf(cf1.x); u.s[5] = f2bf(cf1.y);
    u.s[6] = f2bf(cf1.z); u.s[7] = f2bf(cf1.w);
    *(int4*)&Bs[(wave * 64 + lane) * 8] = u.v;
    cna = fmaf(cf0.x, cf0.x, cna); cna = fmaf(cf0.y, cf0.y, cna);
    cna = fmaf(cf0.z, cf0.z, cna); cna = fmaf(cf0.w, cf0.w, cna);
    cna = fmaf(cf1.x, cf1.x, cna); cna = fmaf(cf1.y, cf1.y, cna);
    cna = fmaf(cf1.z, cf1.z, cna); cna = fmaf(cf1.w, cf1.w, cna);
    __syncthreads();
    s8v a_f[4], b_f[4];
#pragma unroll
    for (int mi = 0; mi < 4; ++mi)
      a_f[mi] = *(const s8v*)&As[(q * 256 + wave * 64 + mi * 16 + r16) * 8];
#pragma unroll
    for (int ni = 0; ni < 4; ++ni)
      b_f[ni] = *(const s8v*)&Bs[(q * 64 + ni * 16 + r16) * 8];
#pragma unroll
    for (int mi = 0; mi < 4; ++mi)
#pragma unroll
      for (int ni = 0; ni < 4; ++ni)
        acc[mi][ni] = __builtin_amdgcn_mfma_f32_16x16x32_bf16(
            a_f[mi], b_f[ni], acc[mi][ni], 0, 0, 0);
  }
  cnp[tid] = cna;
  __syncthreads();
  if (tid < 64)
    cnl[tid] = cnp[tid] + cnp[tid + 64] + cnp[tid + 128] + cnp[tid + 192];
  __syncthreads();
  float* sc = kh ? sc1 : sc0;
#pragma unroll
  for (int mi = 0; mi < 4; ++mi) {
#pragma unroll
    for (int ni = 0; ni < 4; ++ni) {
      int nn = n0 + ni * 16 + r16;
      float cn = cnl[ni * 16 + r16];
#pragma unroll
      for (int r = 0; r < 4; ++r) {
        int mm = m0 + wave * 64 + mi * 16 + q * 4 + r;
        sc[(size_t)mm * 8192 + nn] = -2.f * acc[mi][ni][r] + cn;
      }
    }
  }
}

// ---------------- argmin with exact fp32 recheck ----------------
__global__ void k_argmin(const float* __restrict__ s0, const float* __restrict__ s1,
                         const float* __restrict__ z_e, const float* __restrict__ cb,
                         const float* __restrict__ rowl1, int* __restrict__ idx,
                         float* __restrict__ counts) {
  __shared__ float red[256];
  __shared__ int cand[128];
  __shared__ int ccnt;
  int b = blockIdx.x, tid = threadIdx.x;
  const float* r0 = s0 + (size_t)b * 8192;
  const float* r1 = s1 + (size_t)b * 8192;
  float mn = 1e30f;
  for (int j = tid; j < 8192; j += 256) mn = fminf(mn, r0[j] + r1[j]);
  red[tid] = mn;
  __syncthreads();
  for (int st = 128; st > 0; st >>= 1) {
    if (tid < st) red[tid] = fminf(red[tid], red[tid + st]);
    __syncthreads();
  }
  float minv = red[0];
  // rigorous bf16 rounding bound: 2*2^-8*||z||_1*(1/8192) = ||z||_1/2^20
  float margin = rowl1[b] * (1.0f / 1048576.0f) + 1e-4f;
  if (tid == 0) ccnt = 0;
  __syncthreads();
  for (int j = tid; j < 8192; j += 256) {
    float v = r0[j] + r1[j];
    if (v <= minv + margin) {
      int p = atomicAdd(&ccnt, 1);
      if (p < 128) cand[p] = j;
    }
  }
  __syncthreads();
  int nc = min(ccnt, 128);
  float bestv = 1e30f;
  int bestj = 0x7fffffff;
  const float* zr = z_e + (size_t)b * 8320;
  for (int ci = 0; ci < nc; ++ci) {
    int j = cand[ci];
    const float* cr = cb + (size_t)j * 8320;
    float part = 0.f;
    for (int k = tid; k < 8320; k += 256) {
      float c = cr[k];
      part += c * c - 2.f * zr[k] * c;
    }
    __syncthreads();
    red[tid] = part;
    __syncthreads();
    for (int st = 128; st > 0; st >>= 1) {
      if (tid < st) red[tid] += red[tid + st];
      __syncthreads();
    }
    float sv = red[0];
    if (sv < bestv || (sv == bestv && j < bestj)) { bestv = sv; bestj = j; }
    __syncthreads();
  }
  if (tid == 0) {
    idx[b] = bestj;
    atomicAdd(&counts[bestj], 1.0f);
  }
}

// ---------------- gather zq + emb loss partial ----------------
__global__ void k_gather(const float* __restrict__ cb, const float* __restrict__ z_e,
                         const int* __restrict__ idx, float* __restrict__ zq,
                         float* __restrict__ emb_acc) {
  __shared__ float red[256];
  int b = blockIdx.x, tid = threadIdx.x;
  int j = idx[b];
  const float* cr = cb + (size_t)j * 8320;
  const float* zr = z_e + (size_t)b * 8320;
  float* q = zq + (size_t)b * 8320;
  float part = 0.f;
  for (int k = tid; k < 8320; k += 256) {
    float c = cr[k];
    float d = c - zr[k];
    q[k] = c;
    part += d * d;
  }
  red[tid] = part;
  __syncthreads();
  for (int st = 128; st > 0; st >>= 1) {
    if (tid < st) red[tid] += red[tid + st];
    __syncthreads();
  }
  if (tid == 0) atomicAdd(emb_acc, red[0]);
}

// ---------------- deconv2 -> x_hat ----------------
__global__ void k_dec2(const float* __restrict__ hd, const float* __restrict__ w,
                       const float* __restrict__ bias, float* __restrict__ out) {
  int id = blockIdx.x * 256 + threadIdx.x;
  if (id >= 512 * 260) return;
  int b = id / 260, t = id % 260;
  int u = t >> 1;
  const float* hb = hd + (size_t)b * 8320;
  float acc = bias[0];
  if (t & 1) {
    bool ok = (u + 1 < 130);
    for (int i = 0; i < 64; ++i) {
      acc = fmaf(hb[i * 130 + u], w[i * 4 + 2], acc);
      if (ok) acc = fmaf(hb[i * 130 + u + 1], w[i * 4 + 0], acc);
    }
  } else {
    bool ok = (u >= 1);
    for (int i = 0; i < 64; ++i) {
      if (ok) acc = fmaf(hb[i * 130 + u - 1], w[i * 4 + 3], acc);
      acc = fmaf(hb[i * 130 + u], w[i * 4 + 1], acc);
    }
  }
  out[OUT_XHAT + id] = acc;
}

// ---------------- mt head ----------------
__global__ void k_mt(const float* __restrict__ z_e, const float* __restrict__ mtw,
                     const float* __restrict__ mtb, float* __restrict__ out) {
  __shared__ float red[64];
  int b = blockIdx.x, tid = threadIdx.x;
  int wave = tid >> 6, lane = tid & 63;
  const float* zr = z_e + (size_t)b * 8320;  // first 4160 = channels 0..63
  float acc[16];
#pragma unroll
  for (int n = 0; n < 16; ++n) acc[n] = 0.f;
  for (int k = tid; k < 4160; k += 256) {
    float zv = zr[k];
#pragma unroll
    for (int n = 0; n < 16; ++n) acc[n] = fmaf(zv, mtw[n * 4160 + k], acc[n]);
  }
#pragma unroll
  for (int n = 0; n < 16; ++n) {
    float v = acc[n];
    for (int off = 32; off > 0; off >>= 1) v += __shfl_down(v, off);
    if (lane == 0) red[n * 4 + wave] = v;
  }
  __syncthreads();
  if (tid < 16) {
    float s = red[tid * 4] + red[tid * 4 + 1] + red[tid * 4 + 2] + red[tid * 4 + 3];
    out[OUT_MT + b * 16 + tid] = s + mtb[tid];
  }
}

// ---------------- adv layer 1 (tiled fp32 GEMM, K-split 10, atomic acc) ----
__global__ __launch_bounds__(256) void k_adv1(const float* __restrict__ z_e,
                                              const float* __restrict__ w1,
                                              float* __restrict__ a1) {
  __shared__ float At[32 * 64];
  __shared__ float Bt[32 * 64];
  int bid = blockIdx.x;
  int ksp = bid % 10;
  int nt = (bid / 10) & 3;
  int mt = bid / 40;
  int tid = threadIdx.x;
  int m0 = mt * 64, n0 = nt * 64, kb = ksp * 416;
  int tm = (tid & 15) * 4, tn = (tid >> 4) * 4;
  int sr = tid & 63, sj = (tid >> 6) * 8;
  const float* za = z_e + (size_t)(m0 + sr) * 8320 + 4160 + kb + sj;
  const float* wb = w1 + (size_t)(n0 + sr) * 4160 + kb + sj;
  float acc[4][4];
#pragma unroll
  for (int i = 0; i < 4; ++i)
#pragma unroll
    for (int j = 0; j < 4; ++j) acc[i][j] = 0.f;
  for (int k0 = 0; k0 < 416; k0 += 32) {
    float4 av0 = *(const float4*)(za + k0);
    float4 av1 = *(const float4*)(za + k0 + 4);
    float4 bv0 = *(const float4*)(wb + k0);
    float4 bv1 = *(const float4*)(wb + k0 + 4);
    __syncthreads();
    At[(sj + 0) * 64 + sr] = av0.x; At[(sj + 1) * 64 + sr] = av0.y;
    At[(sj + 2) * 64 + sr] = av0.z; At[(sj + 3) * 64 + sr] = av0.w;
    At[(sj + 4) * 64 + sr] = av1.x; At[(sj + 5) * 64 + sr] = av1.y;
    At[(sj + 6) * 64 + sr] = av1.z; At[(sj + 7) * 64 + sr] = av1.w;
    Bt[(sj + 0) * 64 + sr] = bv0.x; Bt[(sj + 1) * 64 + sr] = bv0.y;
    Bt[(sj + 2) * 64 + sr] = bv0.z; Bt[(sj + 3) * 64 + sr] = bv0.w;
    Bt[(sj + 4) * 64 + sr] = bv1.x; Bt[(sj + 5) * 64 + sr] = bv1.y;
    Bt[(sj + 6) * 64 + sr] = bv1.z; Bt[(sj + 7) * 64 + sr] = bv1.w;
    __syncthreads();
#pragma unroll
    for (int kk = 0; kk < 32; ++kk) {
      float4 aa = *(const float4*)&At[kk * 64 + tm];
      float4 bb = *(const float4*)&Bt[kk * 64 + tn];
      acc[0][0] = fmaf(aa.x, bb.x, acc[0][0]); acc[0][1] = fmaf(aa.x, bb.y, acc[0][1]);
      acc[0][2] = fmaf(aa.x, bb.z, acc[0][2]); acc[0][3] = fmaf(aa.x, bb.w, acc[0][3]);
      acc[1][0] = fmaf(aa.y, bb.x, acc[1][0]); acc[1][1] = fmaf(aa.y, bb.y, acc[1][1]);
      acc[1][2] = fmaf(aa.y, bb.z, acc[1][2]); acc[1][3] = fmaf(aa.y, bb.w, acc[1][3]);
      acc[2][0] = fmaf(aa.z, bb.x, acc[2][0]); acc[2][1] = fmaf(aa.z, bb.y, acc[2][1]);
      acc[2][2] = fmaf(aa.z, bb.z, acc[2][2]); acc[2][3] = fmaf(aa.z, bb.w, acc[2][3]);
      acc[3][0] = fmaf(aa.w, bb.x, acc[3][0]); acc[3][1] = fmaf(aa.w, bb.y, acc[3][1]);
      acc[3][2] = fmaf(aa.w, bb.z, acc[3][2]); acc[3][3] = fmaf(aa.w, bb.w, acc[3][3]);
    }
  }
#pragma unroll
  for (int i = 0; i < 4; ++i)
#pragma unroll
    for (int j = 0; j < 4; ++j)
      atomicAdd(&a1[(size_t)(m0 + tm + i) * 256 + n0 + tn + j], acc[i][j]);
}

// ---------------- adv layers 2+3 fused ----------------
__global__ void k_adv23(const float* __restrict__ a1raw, const float* __restrict__ b1,
                        const float* __restrict__ w2t, const float* __restrict__ b2,
                        const float* __restrict__ w3, const float* __restrict__ b3,
                        float* __restrict__ out) {
  __shared__ float s1[256];
  __shared__ float s2[128];
  int b = blockIdx.x, tid = threadIdx.x;
  s1[tid] = fmaxf(a1raw[(size_t)b * 256 + tid] + b1[tid], 0.f);
  __syncthreads();
  if (tid < 128) {
    float acc = b2[tid];
    for (int k = 0; k < 256; ++k) acc = fmaf(s1[k], w2t[k * 128 + tid], acc);
    s2[tid] = fmaxf(acc, 0.f);
  }
  __syncthreads();
  if (tid < 16) {
    float acc = b3[tid];
    for (int k = 0; k < 128; ++k) acc = fmaf(s2[k], w3[tid * 128 + k], acc);
    out[OUT_ADV + b * 16 + tid] = acc;
  }
}

// ---------------- finalize: emb loss + perplexity ----------------
__global__ void k_fin(const float* __restrict__ counts, const float* __restrict__ emb_acc,
                      const float* __restrict__ beta_p, float* __restrict__ out) {
  __shared__ float red[256];
  int tid = threadIdx.x;
  float part = 0.f;
  for (int j = tid; j < 8192; j += 256) {
    float e = counts[j] * (1.0f / 512.0f);
    part += e * logf(e + 1e-10f);
  }
  red[tid] = part;
  __syncthreads();
  for (int st = 128; st > 0; st >>= 1) {
    if (tid < st) red[tid] += red[tid + st];
    __syncthreads();
  }
  if (tid == 0) {
    out[OUT_PERP] = expf(-red[0]);
    out[0] = (1.f + beta_p[0]) * emb_acc[0] * (1.0f / 4259840.0f);
  }
}

extern "C" void kernel_launch(void* const* d_in, const int* in_sizes, int n_in,
                              void* d_out, int out_size, void* d_ws, size_t ws_size,
                              hipStream_t stream) {
  (void)in_sizes; (void)n_in; (void)out_size; (void)ws_size;
  const float* x   = (const float*)d_in[0];
  const float* cb  = (const float*)d_in[1];
  const float* c1w = (const float*)d_in[2];
  const float* c1b = (const float*)d_in[3];
  const float* c2w = (const float*)d_in[4];
  const float* c2b = (const float*)d_in[5];
  const float* d1w = (const float*)d_in[6];
  const float* d1b = (const float*)d_in[7];
  const float* d2w = (const float*)d_in[8];
  const float* d2b = (const float*)d_in[9];
  const float* mtw = (const float*)d_in[10];
  const float* mtb = (const float*)d_in[11];
  const float* aw1 = (const float*)d_in[12];
  const float* ab1 = (const float*)d_in[13];
  const float* aw2 = (const float*)d_in[14];
  const float* ab2 = (const float*)d_in[15];
  const float* aw3 = (const float*)d_in[16];
  const float* ab3 = (const float*)d_in[17];
  const float* beta = (const float*)d_in[18];
  float* out = (float*)d_out;
  float* W = (float*)d_ws;

  float* counts = W + WS_COUNTS;
  float* embac  = W + WS_EMB;
  float* a1buf  = W + WS_A1;
  float* hbuf   = W + WS_H;     // h, later hd
  float* zebuf  = W + WS_ZE;
  float* sc0    = W + WS_SC0;
  float* sc1    = W + WS_SC1;
  float* zqbuf  = W + WS_ZQ;    // alias over scores (dead by then)
  float* w2t    = W + WS_W2T;
  float* We     = W + WS_WE;
  float* Wo     = W + WS_WO;
  float* w2ta   = W + WS_W2TA;
  float* rowl1  = W + WS_ROWL1;
  int*   idxb   = (int*)(W + WS_IDX);
  short* zbf    = (short*)(W + WS_ZBF);

  k_init<<<(WS_ZERO_N + 255) / 256, 256, 0, stream>>>(W);
  k_prep<<<128, 256, 0, stream>>>(c2w, d1w, aw2, w2t, We, Wo, w2ta);
  k_conv1<<<16640, 256, 0, stream>>>(x, c1w, c1b, hbuf);
  // conv2: src=h (64,130), j=(i,k4), p=2t-1+k, out z_e (b,128,65)
  k_gemm_gather<128><<<520, 256, 0, stream>>>(hbuf, 64, 130, 2, 1, -1, w2t, c2b,
                                              zebuf, 65, 1, 0, 0);
  k_pack<<<512, 256, 0, stream>>>(zebuf, zbf, rowl1);
  k_scores<<<512, 256, 0, stream>>>(cb, zbf, sc0, sc1);
  k_argmin<<<512, 256, 0, stream>>>(sc0, sc1, zebuf, cb, rowl1, idxb, counts);
  k_gather<<<512, 256, 0, stream>>>(cb, zebuf, idxb, zqbuf, embac);
  // deconv1 even t=2u: p=u-1+s, W_e ; odd t=2u+1: p=u+s, W_o ; out hd (b,64,130)
  k_gemm_gather<64><<<520, 256, 0, stream>>>(zqbuf, 128, 65, 1, 0, -1, We, d1b,
                                             hbuf, 130, 2, 0, 1);
  k_gemm_gather<64><<<520, 256, 0, stream>>>(zqbuf, 128, 65, 1, 0, 0, Wo, d1b,
                                             hbuf, 130, 2, 1, 1);
  k_dec2<<<520, 256, 0, stream>>>(hbuf, d2w, d2b, out);
  k_mt<<<512, 256, 0, stream>>>(zebuf, mtw, mtb, out);
  k_adv1<<<320, 256, 0, stream>>>(zebuf, aw1, a1buf);
  k_adv23<<<512, 256, 0, stream>>>(a1buf, ab1, w2ta, ab2, aw3, ab3, out);
  k_fin<<<1, 256, 0, stream>>>(counts, embac, beta, out);
}